// Round 1
// baseline (509.423 us; speedup 1.0000x reference)
//
#include <hip/hip_runtime.h>
#include <hip/hip_bf16.h>

#define B_N   8
#define T_N   32768
#define RESC  128
#define GATEC 256
#define CINC  80
#define CINP  96
#define NT    64
#define HALO  4
#define XROWS 68
#define XSTR  136
#define CSTR  96
#define HSTR  136

#define AP1_ELEMS (16*12*512)  /* 98304 bf16 */
#define AP2_ELEMS (16*3*512)   /* 24576 */
#define AP3_ELEMS (16*4*512)   /* 32768 */

#define OFF_S ((size_t)B_N * RESC * T_N)  /* 33554432 floats: s output offset */

typedef __attribute__((ext_vector_type(8))) short short8;
typedef __attribute__((ext_vector_type(4))) float f32x4;

__device__ __forceinline__ ushort f2bf(float f) {
  union { float f; unsigned int u; } c; c.f = f;
  unsigned int u = c.u;
  u += 0x7fffu + ((u >> 16) & 1u);   // round-to-nearest-even
  return (ushort)(u >> 16);
}
__device__ __forceinline__ float bf2f(ushort s) {
  union { unsigned int u; float f; } c; c.u = ((unsigned int)s) << 16;
  return c.f;
}

// ---------------------------------------------------------------------------
// Prep: weight-norm (fp32) -> bf16 -> pack into MFMA A-fragment order.
// A-frag layout (16x16x32 bf16, m89-verified): A[m = lane&15][k = (lane>>4)*8 + j]
// Apack[((mtile*KS + ks)*64 + lane)*8 + j]
// ---------------------------------------------------------------------------
__global__ __launch_bounds__(256) void wn_pack_kernel(
    const float* __restrict__ conv_v, const float* __restrict__ conv_g,
    const float* __restrict__ lc_v,  const float* __restrict__ lc_g,
    const float* __restrict__ skip_v,const float* __restrict__ skip_g,
    const float* __restrict__ out_v, const float* __restrict__ out_g,
    ushort* __restrict__ Ap1, ushort* __restrict__ Ap2, ushort* __restrict__ Ap3) {
  const int o   = blockIdx.x;   // output channel 0..255
  const int tid = threadIdx.x;  // 0..255
  const int mtg = o >> 4, r = o & 15;
  __shared__ float red[256];

  // ---- conv: norm over 128*3 ----
  float s = 0.f;
  for (int e = tid; e < RESC * 3; e += 256) { float v = conv_v[o * RESC * 3 + e]; s += v * v; }
  red[tid] = s; __syncthreads();
  for (int off = 128; off > 0; off >>= 1) { if (tid < off) red[tid] += red[tid + off]; __syncthreads(); }
  const float csc = conv_g[o] / sqrtf(red[0]);
  __syncthreads();
  for (int e = tid; e < 384; e += 256) {
    const int ks = e >> 5, q = (e >> 3) & 3, j = e & 7;
    const int tap = ks >> 2, ci = (ks & 3) * 32 + q * 8 + j;
    Ap1[((mtg * 12 + ks) * 64 + q * 16 + r) * 8 + j] = f2bf(conv_v[(o * RESC + ci) * 3 + tap] * csc);
  }

  // ---- lc: norm over 80, pad K to 96 ----
  s = 0.f;
  for (int e = tid; e < CINC; e += 256) { float v = lc_v[o * CINC + e]; s += v * v; }
  red[tid] = s; __syncthreads();
  for (int off = 128; off > 0; off >>= 1) { if (tid < off) red[tid] += red[tid + off]; __syncthreads(); }
  const float lsc = lc_g[o] / sqrtf(red[0]);
  __syncthreads();
  for (int e = tid; e < CINP; e += 256) {
    const int ks = e >> 5, q = (e >> 3) & 3, j = e & 7;
    const float wv = (e < CINC) ? lc_v[o * CINC + e] * lsc : 0.f;
    Ap2[((mtg * 3 + ks) * 64 + q * 16 + r) * 8 + j] = f2bf(wv);
  }

  // ---- skip (rows 0..127) / out (rows 128..255): norm over 128 ----
  const float* vrow = (o < 128) ? (skip_v + o * 128) : (out_v + (o - 128) * 128);
  const float  gg   = (o < 128) ? skip_g[o] : out_g[o - 128];
  s = 0.f;
  for (int e = tid; e < 128; e += 256) { float v = vrow[e]; s += v * v; }
  red[tid] = s; __syncthreads();
  for (int off = 128; off > 0; off >>= 1) { if (tid < off) red[tid] += red[tid + off]; __syncthreads(); }
  const float ssc = gg / sqrtf(red[0]);
  for (int e = tid; e < 128; e += 256) {
    const int ks = e >> 5, q = (e >> 3) & 3, j = e & 7;
    Ap3[((mtg * 4 + ks) * 64 + q * 16 + r) * 8 + j] = f2bf(vrow[e] * ssc);
  }
}

// ---------------------------------------------------------------------------
// Fused block: conv(dil=2,causal) + cond GEMM -> gate -> skip/out GEMMs.
// Grid: 4096 = 8 batches x 512 time-tiles of 64. Block: 256 thr = 4 waves.
// Wave w owns output-channel chunk [64w, 64w+64).
// ---------------------------------------------------------------------------
__global__ __launch_bounds__(256) void fused_block_kernel(
    const float* __restrict__ x, const float* __restrict__ cond,
    const float* __restrict__ conv_b, const float* __restrict__ skip_b,
    const float* __restrict__ out_b,
    const ushort* __restrict__ Ap1, const ushort* __restrict__ Ap2,
    const ushort* __restrict__ Ap3,
    float* __restrict__ out) {
  const int tid  = threadIdx.x;
  const int w    = tid >> 6;
  const int lane = tid & 63;
  const int q    = lane >> 4;   // MFMA quad
  const int n    = lane & 15;   // MFMA column (time within 16-tile)
  const int blk  = blockIdx.x;
  const int b    = blk >> 9;
  const int t0   = (blk & 511) << 6;

  __shared__ ushort smem[17408];        // 34816 B
  ushort* xs  = smem;                   // [68][136] x-tile, t-major (rows = t - (t0-4))
  ushort* cs  = smem + XROWS * XSTR;    // [64][96] cond-tile
  ushort* hsA = smem;                   // [64][136] tanh half (aliases xs after barrier)
  ushort* hsB = smem + NT * HSTR;       // [64][136] sigmoid half

  // ================= stage x tile (transpose [c][t] -> [t][c], bf16) =======
  {
    const int g4 = tid >> 3;            // 0..31 -> channels 4*g4..+3
    const int c0 = g4 << 2;
    const int tt = (tid & 7) << 3;      // 8 timesteps per thread
    const float* xp = x + ((size_t)b * RESC + c0) * T_N + t0 + tt;
    float va[4][8];
#pragma unroll
    for (int rr = 0; rr < 4; ++rr) {
      const float4* rp = (const float4*)(xp + (size_t)rr * T_N);
      const float4 a0 = rp[0], a1 = rp[1];
      va[rr][0] = a0.x; va[rr][1] = a0.y; va[rr][2] = a0.z; va[rr][3] = a0.w;
      va[rr][4] = a1.x; va[rr][5] = a1.y; va[rr][6] = a1.z; va[rr][7] = a1.w;
    }
#pragma unroll
    for (int ss = 0; ss < 8; ++ss) {
      const unsigned lo = (unsigned)f2bf(va[0][ss]) | ((unsigned)f2bf(va[1][ss]) << 16);
      const unsigned hi = (unsigned)f2bf(va[2][ss]) | ((unsigned)f2bf(va[3][ss]) << 16);
      *(uint2*)&xs[(HALO + tt + ss) * XSTR + c0] = make_uint2(lo, hi);
    }
  }
  // halo rows 0..3 = t0-4..t0-1 (zeros at sequence start = causal left-pad)
  if (tid < RESC) {
    float h0 = 0.f, h1 = 0.f, h2 = 0.f, h3 = 0.f;
    if (t0 > 0) {
      const float4 hv = *(const float4*)(x + ((size_t)b * RESC + tid) * T_N + t0 - 4);
      h0 = hv.x; h1 = hv.y; h2 = hv.z; h3 = hv.w;
    }
    xs[0 * XSTR + tid] = f2bf(h0);
    xs[1 * XSTR + tid] = f2bf(h1);
    xs[2 * XSTR + tid] = f2bf(h2);
    xs[3 * XSTR + tid] = f2bf(h3);
  }
  // ================= stage cond tile ([c][t] -> [t][c], pad 80->96) ========
  if (tid < 160) {
    const int g4 = tid >> 3;            // 0..19
    const int c0 = g4 << 2;
    const int tt = (tid & 7) << 3;
    const float* cp = cond + ((size_t)b * CINC + c0) * T_N + t0 + tt;
    float va[4][8];
#pragma unroll
    for (int rr = 0; rr < 4; ++rr) {
      const float4* rp = (const float4*)(cp + (size_t)rr * T_N);
      const float4 a0 = rp[0], a1 = rp[1];
      va[rr][0] = a0.x; va[rr][1] = a0.y; va[rr][2] = a0.z; va[rr][3] = a0.w;
      va[rr][4] = a1.x; va[rr][5] = a1.y; va[rr][6] = a1.z; va[rr][7] = a1.w;
    }
#pragma unroll
    for (int ss = 0; ss < 8; ++ss) {
      const unsigned lo = (unsigned)f2bf(va[0][ss]) | ((unsigned)f2bf(va[1][ss]) << 16);
      const unsigned hi = (unsigned)f2bf(va[2][ss]) | ((unsigned)f2bf(va[3][ss]) << 16);
      *(uint2*)&cs[(tt + ss) * CSTR + c0] = make_uint2(lo, hi);
    }
  } else {
    const int e0 = tid - 160;           // zero-fill channels 80..95
    for (int z = e0; z < 512; z += 96) {
      const int t = z >> 3, cp2 = z & 7;
      *(unsigned int*)&cs[t * CSTR + CINC + cp2 * 2] = 0u;
    }
  }
  __syncthreads();

  // ================= GEMM1 (conv, K=384) + GEMM2 (lc, K=96) into acc ======
  f32x4 acc[4][4];
#pragma unroll
  for (int mt = 0; mt < 4; ++mt) {
    const float4 cb = *(const float4*)(conv_b + w * 64 + mt * 16 + q * 4);
#pragma unroll
    for (int nt = 0; nt < 4; ++nt) acc[mt][nt] = (f32x4){cb.x, cb.y, cb.z, cb.w};
  }
#pragma unroll
  for (int ks = 0; ks < 12; ++ks) {
    const int tap = ks >> 2;
    const int cb2 = (ks & 3) << 5;
    short8 af[4], bfr[4];
#pragma unroll
    for (int mt = 0; mt < 4; ++mt)
      af[mt] = *(const short8*)(Ap1 + ((w * 4 + mt) * 12 + ks) * 512 + lane * 8);
#pragma unroll
    for (int nt = 0; nt < 4; ++nt)
      bfr[nt] = *(const short8*)&xs[(nt * 16 + n + tap * 2) * XSTR + cb2 + q * 8];
#pragma unroll
    for (int mt = 0; mt < 4; ++mt)
#pragma unroll
      for (int nt = 0; nt < 4; ++nt)
        acc[mt][nt] = __builtin_amdgcn_mfma_f32_16x16x32_bf16(af[mt], bfr[nt], acc[mt][nt], 0, 0, 0);
  }
#pragma unroll
  for (int ks = 0; ks < 3; ++ks) {
    short8 af[4], bfr[4];
#pragma unroll
    for (int mt = 0; mt < 4; ++mt)
      af[mt] = *(const short8*)(Ap2 + ((w * 4 + mt) * 3 + ks) * 512 + lane * 8);
#pragma unroll
    for (int nt = 0; nt < 4; ++nt)
      bfr[nt] = *(const short8*)&cs[(nt * 16 + n) * CSTR + ks * 32 + q * 8];
#pragma unroll
    for (int mt = 0; mt < 4; ++mt)
#pragma unroll
      for (int nt = 0; nt < 4; ++nt)
        acc[mt][nt] = __builtin_amdgcn_mfma_f32_16x16x32_bf16(af[mt], bfr[nt], acc[mt][nt], 0, 0, 0);
  }
  __syncthreads();   // all xs/cs reads done; safe to overwrite aliased region

  // ================= activations -> LDS (waves 0,1: tanh; 2,3: sigmoid) ===
  const int colbase = (w & 1) << 6;
  {
    ushort* hdst = (w < 2) ? hsA : hsB;
#pragma unroll
    for (int mt = 0; mt < 4; ++mt)
#pragma unroll
      for (int nt = 0; nt < 4; ++nt) {
        const f32x4 v = acc[mt][nt];
        float r0, r1, r2, r3;
        if (w < 2) {
          r0 = 1.f - 2.f / (__expf(2.f * v[0]) + 1.f);
          r1 = 1.f - 2.f / (__expf(2.f * v[1]) + 1.f);
          r2 = 1.f - 2.f / (__expf(2.f * v[2]) + 1.f);
          r3 = 1.f - 2.f / (__expf(2.f * v[3]) + 1.f);
        } else {
          r0 = 1.f / (1.f + __expf(-v[0]));
          r1 = 1.f / (1.f + __expf(-v[1]));
          r2 = 1.f / (1.f + __expf(-v[2]));
          r3 = 1.f / (1.f + __expf(-v[3]));
        }
        const unsigned lo = (unsigned)f2bf(r0) | ((unsigned)f2bf(r1) << 16);
        const unsigned hi = (unsigned)f2bf(r2) | ((unsigned)f2bf(r3) << 16);
        *(uint2*)&hdst[(nt * 16 + n) * HSTR + colbase + mt * 16 + q * 4] = make_uint2(lo, hi);
      }
  }
  __syncthreads();

  // ================= g = tanh * sigmoid (into hsA, in place) ==============
  {
    const int prow = tid >> 2;          // 0..63
    const int pc0  = (tid & 3) << 5;
#pragma unroll
    for (int s2 = 0; s2 < 8; ++s2) {
      const int col = pc0 + (s2 << 2);
      const uint2 ua = *(uint2*)&hsA[prow * HSTR + col];
      const uint2 ub = *(uint2*)&hsB[prow * HSTR + col];
      const float a0 = bf2f((ushort)ua.x), a1 = bf2f((ushort)(ua.x >> 16));
      const float a2 = bf2f((ushort)ua.y), a3 = bf2f((ushort)(ua.y >> 16));
      const float b0 = bf2f((ushort)ub.x), b1 = bf2f((ushort)(ub.x >> 16));
      const float b2 = bf2f((ushort)ub.y), b3 = bf2f((ushort)(ub.y >> 16));
      const unsigned lo = (unsigned)f2bf(a0 * b0) | ((unsigned)f2bf(a1 * b1) << 16);
      const unsigned hi = (unsigned)f2bf(a2 * b2) | ((unsigned)f2bf(a3 * b3) << 16);
      *(uint2*)&hsA[prow * HSTR + col] = make_uint2(lo, hi);
    }
  }
  __syncthreads();

  // ================= GEMM3: [skip;out] = Wso @ g, K=128 ===================
  {
    const float* bias = (w < 2) ? skip_b : out_b;
#pragma unroll
    for (int mt = 0; mt < 4; ++mt) {
      const float4 bb = *(const float4*)(bias + colbase + mt * 16 + q * 4);
#pragma unroll
      for (int nt = 0; nt < 4; ++nt) acc[mt][nt] = (f32x4){bb.x, bb.y, bb.z, bb.w};
    }
#pragma unroll
    for (int ks = 0; ks < 4; ++ks) {
      short8 af[4], bfr[4];
#pragma unroll
      for (int mt = 0; mt < 4; ++mt)
        af[mt] = *(const short8*)(Ap3 + ((w * 4 + mt) * 4 + ks) * 512 + lane * 8);
#pragma unroll
      for (int nt = 0; nt < 4; ++nt)
        bfr[nt] = *(const short8*)&hsA[(nt * 16 + n) * HSTR + ks * 32 + q * 8];
#pragma unroll
      for (int mt = 0; mt < 4; ++mt)
#pragma unroll
        for (int nt = 0; nt < 4; ++nt)
          acc[mt][nt] = __builtin_amdgcn_mfma_f32_16x16x32_bf16(af[mt], bfr[nt], acc[mt][nt], 0, 0, 0);
    }
  }

  // ================= epilogue: stores (s for waves 0,1; o+residual 2,3) ===
#pragma unroll
  for (int mt = 0; mt < 4; ++mt)
#pragma unroll
    for (int nt = 0; nt < 4; ++nt) {
      const int ch = colbase + mt * 16 + q * 4;
      const int t  = t0 + nt * 16 + n;
      const f32x4 v = acc[mt][nt];
      if (w < 2) {
        float* dst = out + OFF_S + ((size_t)(b * RESC + ch)) * T_N + t;
#pragma unroll
        for (int i = 0; i < 4; ++i) dst[(size_t)i * T_N] = v[i];
      } else {
        const float* xr = x + ((size_t)(b * RESC + ch)) * T_N + t;
        float* dst = out + ((size_t)(b * RESC + ch)) * T_N + t;
#pragma unroll
        for (int i = 0; i < 4; ++i) dst[(size_t)i * T_N] = v[i] + xr[(size_t)i * T_N];
      }
    }
}

extern "C" void kernel_launch(void* const* d_in, const int* in_sizes, int n_in,
                              void* d_out, int out_size, void* d_ws, size_t ws_size,
                              hipStream_t stream) {
  const float* x      = (const float*)d_in[0];
  const float* cond   = (const float*)d_in[1];
  const float* conv_v = (const float*)d_in[2];
  const float* conv_g = (const float*)d_in[3];
  const float* conv_b = (const float*)d_in[4];
  const float* lc_v   = (const float*)d_in[5];
  const float* lc_g   = (const float*)d_in[6];
  const float* skip_v = (const float*)d_in[7];
  const float* skip_g = (const float*)d_in[8];
  const float* skip_b = (const float*)d_in[9];
  const float* out_v  = (const float*)d_in[10];
  const float* out_g  = (const float*)d_in[11];
  const float* out_b  = (const float*)d_in[12];

  ushort* Ap1 = (ushort*)d_ws;
  ushort* Ap2 = Ap1 + AP1_ELEMS;
  ushort* Ap3 = Ap2 + AP2_ELEMS;

  hipLaunchKernelGGL(wn_pack_kernel, dim3(256), dim3(256), 0, stream,
                     conv_v, conv_g, lc_v, lc_g, skip_v, skip_g, out_v, out_g,
                     Ap1, Ap2, Ap3);
  hipLaunchKernelGGL(fused_block_kernel, dim3(4096), dim3(256), 0, stream,
                     x, cond, conv_b, skip_b, out_b, Ap1, Ap2, Ap3, (float*)d_out);
}